// Round 1
// baseline (759.113 us; speedup 1.0000x reference)
//
#include <hip/hip_runtime.h>

#define N_TOK 2048
#define B_SZ  8
#define E_DIM 256
#define H_DIM 512
#define TPG   (N_TOK / 64)     // 32 key-tiles per ks-group (2 groups cover 64)

typedef __attribute__((ext_vector_type(8))) short bf16x8;
typedef __attribute__((ext_vector_type(4))) float f32x4;
typedef __attribute__((ext_vector_type(4))) unsigned short u16x4;

__device__ __forceinline__ unsigned short f2bf(float f) {
    union { float f; unsigned u; } v; v.f = f;
    unsigned r = v.u + 0x7FFF + ((v.u >> 16) & 1);   // RNE
    return (unsigned short)(r >> 16);
}
__device__ __forceinline__ float bf2f(unsigned short b) {
    union { unsigned u; float f; } v; v.u = ((unsigned)b) << 16;
    return v.f;
}

// ---- Kernel 1: fused prep (vectorized) -------------------------------------
// blocks [0, 4096): row-normalize x -> Xn bf16 (B,N,E). One row per wave:
//   float4 loads, 64-lane shfl reduce, ushort4 stores. 16B units XOR-swizzled
//   (unit u of row n stored at position u ^ (n & 7)).
// blocks [4096, 12288): pack h (N,B,H) f32 -> Vp (B, N/32, H, 32) bf16,
//   swizzled: 16B unit (hc, jg) stored at hc*4 + (jg ^ ((hc>>1)&3)).
//   LDS 32x32 transpose, ushort4 stores.
__global__ void prep_kernel(const float* __restrict__ x,
                            const float* __restrict__ hptr,
                            unsigned short* __restrict__ Xn,
                            unsigned short* __restrict__ Vp) {
    int bid = blockIdx.x;
    int t = threadIdx.x;
    if (bid < (N_TOK * B_SZ) / 4) {
        // ---- norm path: 4 rows/block, one per wave ----
        int w = t >> 6, lane = t & 63;
        int r = bid * 4 + w;                 // row in x memory order: r = n*B + b
        int n = r >> 3, b = r & 7;
        float4 v = *(const float4*)(x + (size_t)r * E_DIM + lane * 4);
        float s = v.x * v.x + v.y * v.y + v.z * v.z + v.w * v.w;
        #pragma unroll
        for (int o = 32; o > 0; o >>= 1) s += __shfl_xor(s, o);
        float rn = 1.0f / sqrtf(s);
        u16x4 pk;
        pk[0] = f2bf(v.x * rn); pk[1] = f2bf(v.y * rn);
        pk[2] = f2bf(v.z * rn); pk[3] = f2bf(v.w * rn);
        int u = lane >> 1, half = lane & 1;
        *(u16x4*)(Xn + ((size_t)b * N_TOK + n) * E_DIM
                     + (size_t)((u ^ (n & 7)) * 8 + half * 4)) = pk;
    } else {
        // ---- pack-V path ----
        int lin = bid - (N_TOK * B_SZ) / 4;    // 8192 blocks: (64, 16, 8)
        int jb = lin & 63, hb = (lin >> 6) & 15, b = lin >> 10;
        __shared__ float tile[32][33];
        int j0 = jb * 32, h0 = hb * 32;
        int tx = t & 31, ty = t >> 5;          // 32 x 8
        #pragma unroll
        for (int it = 0; it < 4; it++) {
            int j = j0 + ty + it * 8;
            tile[ty + it * 8][tx] = hptr[((size_t)j * B_SZ + b) * H_DIM + h0 + tx];
        }
        __syncthreads();
        size_t base = ((size_t)b * (N_TOK / 32) + jb) * (H_DIM * 32);
        int hcl = t >> 3, jg = (t >> 1) & 3, half = t & 1;
        int hc = h0 + hcl;
        u16x4 pk;
        #pragma unroll
        for (int k = 0; k < 4; k++)
            pk[k] = f2bf(tile[jg * 8 + half * 4 + k][hcl]);
        *(u16x4*)(Vp + base + (size_t)(hc * 4 + (jg ^ ((hcl >> 1) & 3))) * 8
                     + half * 4) = pk;
    }
}

// ---- Kernel 2: fused flash attention, intra-block split-K ------------------
// Fixed-shift softmax (scores in [-1,1] -> P = exp(s-1)) makes partial (O, l)
// over disjoint key ranges EXACTLY additive: no max tracking, no rescale.
// 512 threads = 8 waves: ks = w>>2 splits the 64 key-tiles in half (32 each),
// (rg, hh) = ((w>>1)&1, w&1) as before (16 q-rows x 256 h-cols per wave,
// QK dup x2 over hh). Each ks-group has its own double-buffered K LDS.
// Epilogue: ks=1 dumps (O, l) into LDS (reusing Kbuf), ks=0 adds, normalizes,
// writes out. Grid (8, 64): 2 blocks/CU x 8 waves = 4 waves/SIMD.
#define PT_STRIDE 40   // shorts

__launch_bounds__(512, 4)
__global__ void flash_kernel(const unsigned short* __restrict__ Xn,
                             const unsigned short* __restrict__ Vp,
                             float* __restrict__ out,
                             float* __restrict__ sumsq) {
    __shared__ __attribute__((aligned(16))) unsigned short Kbuf[2][2][32 * 256];
    __shared__ __attribute__((aligned(16))) unsigned short Pt[8][16 * PT_STRIDE];

    int b  = blockIdx.x;           // batch: linear-id % 8 == b -> XCD-pinned
    int q0 = blockIdx.y * 32;
    int t = threadIdx.x;
    int w = t >> 6, lane = t & 63;
    int quad = lane >> 4, nm = lane & 15;
    int ks = w >> 2, rg = (w >> 1) & 1, hh = w & 1, wl = w & 3;

    const unsigned short* Kbase = Xn + (size_t)b * N_TOK * E_DIM;
    const unsigned short* Qrow =
        Xn + ((size_t)b * N_TOK + q0 + rg * 16 + nm) * E_DIM;
    const unsigned short* Vtile0 = Vp + (size_t)b * (N_TOK / 32) * (H_DIM * 32);

    // Q fragments (swizzled layout: unit (ec*4+quad) ^ (row&7))
    bf16x8 qf[8];
    #pragma unroll
    for (int ec = 0; ec < 8; ec++)
        qf[ec] = *(const bf16x8*)(Qrow + (size_t)(((ec * 4 + quad) ^ (nm & 7)) * 8));

    f32x4 O[16];
    #pragma unroll
    for (int i = 0; i < 16; i++) O[i] = (f32x4){0.f, 0.f, 0.f, 0.f};
    float l_lane[4];
    #pragma unroll
    for (int r = 0; r < 4; r++) l_lane[r] = 0.0f;

    // K staging: each ks-group's 4 waves copy the group's 16KB tile
    auto stage = [&](int tile, int buf) {
        const unsigned short* src0 = Kbase + (size_t)tile * 32 * E_DIM;
        #pragma unroll
        for (int k = 0; k < 4; k++) {
            int chunk = wl * 4 + k;                // 0..15, 1KB each
            __builtin_amdgcn_global_load_lds(
                (const __attribute__((address_space(1))) unsigned int*)
                    (src0 + (size_t)chunk * 512 + lane * 8),
                (__attribute__((address_space(3))) unsigned int*)
                    (&Kbuf[ks][buf][chunk * 512]),
                16, 0, 0);
        }
    };

    int tile0 = ks * TPG;                          // 0 or 32
    stage(tile0, 0);
    int vswz = (quad ^ ((nm >> 1) & 3)) * 8;

    for (int ii = 0; ii < TPG; ++ii) {
        __syncthreads();                 // drains staging of tile tile0+ii
        int cur = ii & 1;
        int it = tile0 + ii;

        // ---- V fragment prefetch (this iter) ----
        const unsigned short* Vt = Vtile0 + (size_t)it * (H_DIM * 32);
        bf16x8 vf[16];
        #pragma unroll
        for (int tt = 0; tt < 16; tt++) {
            int hc = hh * 256 + tt * 16 + nm;
            vf[tt] = *(const bf16x8*)(Vt + (size_t)(hc * 4) * 8 + vswz);
        }

        if (ii + 1 < TPG) stage(tile0 + ii + 1, cur ^ 1);
        const unsigned short* KB = &Kbuf[ks][cur][0];

        // ---- QK^T: 16 q-rows x 32 keys, K=256 ----
        f32x4 s0 = (f32x4){0.f,0.f,0.f,0.f}, s1 = (f32x4){0.f,0.f,0.f,0.f};
        #pragma unroll
        for (int ec = 0; ec < 8; ec++) {
            int u = ((ec * 4 + quad) ^ (nm & 7)) * 8;
            bf16x8 kf0 = *(const bf16x8*)(KB + nm * 256 + u);
            bf16x8 kf1 = *(const bf16x8*)(KB + (16 + nm) * 256 + u);
            s0 = __builtin_amdgcn_mfma_f32_16x16x32_bf16(qf[ec], kf0, s0, 0, 0, 0);
            s1 = __builtin_amdgcn_mfma_f32_16x16x32_bf16(qf[ec], kf1, s1, 0, 0, 0);
        }

        // ---- fixed-shift softmax: P = exp(s-1), purely elementwise ----
        #pragma unroll
        for (int r = 0; r < 4; r++) {
            unsigned short pb0 = f2bf(__expf(s0[r] - 1.0f));
            unsigned short pb1 = f2bf(__expf(s1[r] - 1.0f));
            l_lane[r] += bf2f(pb0) + bf2f(pb1);
            Pt[w][(quad * 4 + r) * PT_STRIDE + nm]      = pb0;
            Pt[w][(quad * 4 + r) * PT_STRIDE + 16 + nm] = pb1;
        }

        asm volatile("s_waitcnt lgkmcnt(0)" ::: "memory");
        __builtin_amdgcn_wave_barrier();
        bf16x8 pf = *(const bf16x8*)(&Pt[w][nm * PT_STRIDE + quad * 8]);

        // ---- PV (16 col-tiles x K=32), no rescale needed ----
        #pragma unroll
        for (int tt = 0; tt < 16; tt++)
            O[tt] = __builtin_amdgcn_mfma_f32_16x16x32_bf16(pf, vf[tt], O[tt], 0, 0, 0);
    }

    // ---- cross-group combine (partials are exactly additive) ----
    __syncthreads();                     // everyone done with Kbuf/Pt
    float* Ox = (float*)&Kbuf[0][0][0];  // 64 KB: 4 regions x 16 KB
    float* Lx = (float*)&Pt[0][0];       // 4 KB used
    int pr = rg * 2 + hh;
    if (ks == 1) {
        float* dst = Ox + pr * (16 * 256);
        #pragma unroll
        for (int tt = 0; tt < 16; tt++)
            *(f32x4*)(dst + (tt * 64 + lane) * 4) = O[tt];
        #pragma unroll
        for (int r = 0; r < 4; r++)
            Lx[pr * 256 + lane * 4 + r] = l_lane[r];
    }
    __syncthreads();
    if (ks == 0) {
        float* src = Ox + pr * (16 * 256);
        #pragma unroll
        for (int tt = 0; tt < 16; tt++) {
            f32x4 o2 = *(const f32x4*)(src + (tt * 64 + lane) * 4);
            O[tt] += o2;
        }
        #pragma unroll
        for (int r = 0; r < 4; r++)
            l_lane[r] += Lx[pr * 256 + lane * 4 + r];

        // reduce l over the 16 key-lanes, normalize, write, sumsq
        float linv[4];
        #pragma unroll
        for (int r = 0; r < 4; r++) {
            float lv = l_lane[r];
            #pragma unroll
            for (int o = 1; o < 16; o <<= 1) lv += __shfl_xor(lv, o);
            linv[r] = 1.0f / lv;
        }

        float ss = 0.0f;
        #pragma unroll
        for (int tt = 0; tt < 16; tt++) {
            #pragma unroll
            for (int r = 0; r < 4; r++) {
                float val = O[tt][r] * linv[r];
                int row = q0 + rg * 16 + quad * 4 + r;
                int col = hh * 256 + tt * 16 + nm;
                out[((size_t)row * B_SZ + b) * H_DIM + col] = val;
                ss += val * val;
            }
        }
        #pragma unroll
        for (int o = 1; o < 64; o <<= 1) ss += __shfl_xor(ss, o);
        if (lane == 0) atomicAdd(sumsq, ss);
    }
}

// ---- Kernel 3: global-norm rescale ----------------------------------------
__global__ void scale_kernel(float* __restrict__ out,
                             const float* __restrict__ sumsq) {
    size_t idx = ((size_t)blockIdx.x * blockDim.x + threadIdx.x) * 4;
    float rs = 1.0f / sqrtf(*sumsq);
    float4 v = *(float4*)(out + idx);
    v.x *= rs; v.y *= rs; v.z *= rs; v.w *= rs;
    *(float4*)(out + idx) = v;
}

extern "C" void kernel_launch(void* const* d_in, const int* in_sizes, int n_in,
                              void* d_out, int out_size, void* d_ws, size_t ws_size,
                              hipStream_t stream) {
    const float* x = (const float*)d_in[0];
    const float* h = (const float*)d_in[1];
    float* out = (float*)d_out;

    unsigned short* Xn = (unsigned short*)d_ws;                  // 8.4 MB
    unsigned short* Vp = Xn + (size_t)B_SZ * N_TOK * E_DIM;      // 16.8 MB
    float* sumsq = (float*)(Vp + (size_t)B_SZ * N_TOK * H_DIM);  // 4 B

    hipMemsetAsync(sumsq, 0, sizeof(float), stream);
    prep_kernel<<<(N_TOK * B_SZ) / 4 + (N_TOK / 32) * (H_DIM / 32) * B_SZ,
                  256, 0, stream>>>(x, h, Xn, Vp);
    flash_kernel<<<dim3(B_SZ, N_TOK / 32), 512, 0, stream>>>(Xn, Vp, out, sumsq);
    scale_kernel<<<out_size / (4 * 256), 256, 0, stream>>>(out, sumsq);
}

// Round 2
// 223.200 us; speedup vs baseline: 3.4010x; 3.4010x over previous
//
#include <hip/hip_runtime.h>

#define N_TOK 2048
#define B_SZ  8
#define E_DIM 256
#define H_DIM 512
#define ITERS (N_TOK / 32)     // 64

typedef __attribute__((ext_vector_type(8))) short bf16x8;
typedef __attribute__((ext_vector_type(4))) float f32x4;
typedef __attribute__((ext_vector_type(4))) unsigned short u16x4;

__device__ __forceinline__ unsigned short f2bf(float f) {
    union { float f; unsigned u; } v; v.f = f;
    unsigned r = v.u + 0x7FFF + ((v.u >> 16) & 1);   // RNE
    return (unsigned short)(r >> 16);
}
__device__ __forceinline__ float bf2f(unsigned short b) {
    union { unsigned u; float f; } v; v.u = ((unsigned)b) << 16;
    return v.f;
}

// ---- Kernel 1: fused prep (vectorized, verified in round 1) ----------------
// blocks [0, 4096): row-normalize x -> Xn bf16 (B,N,E). One row per wave:
//   float4 loads, 64-lane shfl reduce, ushort4 stores. 16B units XOR-swizzled
//   (unit u of row n stored at position u ^ (n & 7)).
// blocks [4096, 12288): pack h (N,B,H) f32 -> Vp (B, N/32, H, 32) bf16,
//   swizzled: 16B unit (hc, jg) stored at hc*4 + (jg ^ ((hc>>1)&3)).
__global__ void prep_kernel(const float* __restrict__ x,
                            const float* __restrict__ hptr,
                            unsigned short* __restrict__ Xn,
                            unsigned short* __restrict__ Vp) {
    int bid = blockIdx.x;
    int t = threadIdx.x;
    if (bid < (N_TOK * B_SZ) / 4) {
        // ---- norm path: 4 rows/block, one per wave ----
        int w = t >> 6, lane = t & 63;
        int r = bid * 4 + w;                 // row in x memory order: r = n*B + b
        int n = r >> 3, b = r & 7;
        float4 v = *(const float4*)(x + (size_t)r * E_DIM + lane * 4);
        float s = v.x * v.x + v.y * v.y + v.z * v.z + v.w * v.w;
        #pragma unroll
        for (int o = 32; o > 0; o >>= 1) s += __shfl_xor(s, o);
        float rn = 1.0f / sqrtf(s);
        u16x4 pk;
        pk[0] = f2bf(v.x * rn); pk[1] = f2bf(v.y * rn);
        pk[2] = f2bf(v.z * rn); pk[3] = f2bf(v.w * rn);
        int u = lane >> 1, half = lane & 1;
        *(u16x4*)(Xn + ((size_t)b * N_TOK + n) * E_DIM
                     + (size_t)((u ^ (n & 7)) * 8 + half * 4)) = pk;
    } else {
        // ---- pack-V path ----
        int lin = bid - (N_TOK * B_SZ) / 4;    // 8192 blocks: (64, 16, 8)
        int jb = lin & 63, hb = (lin >> 6) & 15, b = lin >> 10;
        __shared__ float tile[32][33];
        int j0 = jb * 32, h0 = hb * 32;
        int tx = t & 31, ty = t >> 5;          // 32 x 8
        #pragma unroll
        for (int it = 0; it < 4; it++) {
            int j = j0 + ty + it * 8;
            tile[ty + it * 8][tx] = hptr[((size_t)j * B_SZ + b) * H_DIM + h0 + tx];
        }
        __syncthreads();
        size_t base = ((size_t)b * (N_TOK / 32) + jb) * (H_DIM * 32);
        int hcl = t >> 3, jg = (t >> 1) & 3, half = t & 1;
        int hc = h0 + hcl;
        u16x4 pk;
        #pragma unroll
        for (int k = 0; k < 4; k++)
            pk[k] = f2bf(tile[jg * 8 + half * 4 + k][hcl]);
        *(u16x4*)(Vp + base + (size_t)(hc * 4 + (jg ^ ((hcl >> 1) & 3))) * 8
                     + half * 4) = pk;
    }
}

// ---- Kernel 2: fused flash attention, shared-P (no QK duplication) ---------
// 256 threads, 4 waves: rg = w>>1 picks the 16-q-row group, kh = w&1 picks
// BOTH the 16-key half this wave computes in QK^T AND the 256-h-col half it
// owns in PV. QK^T per wave: 8 MFMAs + 8 K ds_reads (was 16+16 with hh
// duplication). exp(s-1) published to shared Pt[rg]; the kh pair syncs with a
// RAW s_barrier (lgkmcnt-only wait, vmcnt stays in flight so the async K
// staging and V prefetch keep running). Fixed-shift softmax: scores are
// cosine sims in [-1,1], P = exp(s-1), l accumulates per-lane; cross-kh l
// combined at epilogue via tiny LDS.
#define PT_STRIDE 40   // shorts

__launch_bounds__(256, 2)
__global__ void flash_kernel(const unsigned short* __restrict__ Xn,
                             const unsigned short* __restrict__ Vp,
                             float* __restrict__ out,
                             float* __restrict__ sumsq) {
    __shared__ __attribute__((aligned(16))) unsigned short Kbuf[2][32 * 256];
    __shared__ __attribute__((aligned(16))) unsigned short Pt[2][16 * PT_STRIDE];
    __shared__ float Lred[2][2][16];

    int b  = blockIdx.x;           // batch: linear-id % 8 == b -> XCD-pinned
    int q0 = blockIdx.y * 32;
    int t = threadIdx.x;
    int w = t >> 6, lane = t & 63;
    int quad = lane >> 4, nm = lane & 15;
    int rg = w >> 1, kh = w & 1;   // kh doubles as PV col-half (hh)

    const unsigned short* Kbase = Xn + (size_t)b * N_TOK * E_DIM;
    const unsigned short* Qrow =
        Xn + ((size_t)b * N_TOK + q0 + rg * 16 + nm) * E_DIM;
    const unsigned short* Vtile0 = Vp + (size_t)b * (N_TOK / 32) * (H_DIM * 32);

    // Q fragments (swizzled layout: unit (ec*4+quad) ^ (row&7))
    bf16x8 qf[8];
    #pragma unroll
    for (int ec = 0; ec < 8; ec++)
        qf[ec] = *(const bf16x8*)(Qrow + (size_t)(((ec * 4 + quad) ^ (nm & 7)) * 8));

    f32x4 O[16];
    #pragma unroll
    for (int i = 0; i < 16; i++) O[i] = (f32x4){0.f, 0.f, 0.f, 0.f};
    float l_lane[4];
    #pragma unroll
    for (int r = 0; r < 4; r++) l_lane[r] = 0.0f;

    // K staging: 4 waves cooperatively copy the 16KB tile (swizzle pre-baked)
    auto stage = [&](int tile, int buf) {
        const unsigned short* src0 = Kbase + (size_t)tile * 32 * E_DIM;
        #pragma unroll
        for (int k = 0; k < 4; k++) {
            int chunk = w * 4 + k;                 // 0..15, 1KB each
            __builtin_amdgcn_global_load_lds(
                (const __attribute__((address_space(1))) unsigned int*)
                    (src0 + (size_t)chunk * 512 + lane * 8),
                (__attribute__((address_space(3))) unsigned int*)
                    (&Kbuf[buf][chunk * 512]),
                16, 0, 0);
        }
    };

    stage(0, 0);
    int vswz = (quad ^ ((nm >> 1) & 3)) * 8;
    int krow = kh * 16 + nm;       // the key row this wave computes in QK^T

    for (int it = 0; it < ITERS; ++it) {
        __syncthreads();                 // drains staging of tile `it`
        int cur = it & 1;

        // ---- V fragment prefetch (this iter), contiguous 1KB per instr ----
        const unsigned short* Vt = Vtile0 + (size_t)it * (H_DIM * 32);
        bf16x8 vf[16];
        #pragma unroll
        for (int tt = 0; tt < 16; tt++) {
            int hc = kh * 256 + tt * 16 + nm;
            vf[tt] = *(const bf16x8*)(Vt + (size_t)(hc * 4) * 8 + vswz);
        }

        if (it + 1 < ITERS) stage(it + 1, cur ^ 1);
        const unsigned short* KB = &Kbuf[cur][0];

        // ---- QK^T: 16 q-rows x 16 keys (this wave's half), K=256 ----
        // two 4-deep dependent chains for ILP, summed at the end
        f32x4 sa = (f32x4){0.f,0.f,0.f,0.f}, sb = (f32x4){0.f,0.f,0.f,0.f};
        #pragma unroll
        for (int ec = 0; ec < 4; ec++) {
            int u0 = (((2*ec)   * 4 + quad) ^ (nm & 7)) * 8;
            int u1 = (((2*ec+1) * 4 + quad) ^ (nm & 7)) * 8;
            bf16x8 kf0 = *(const bf16x8*)(KB + krow * 256 + u0);
            bf16x8 kf1 = *(const bf16x8*)(KB + krow * 256 + u1);
            sa = __builtin_amdgcn_mfma_f32_16x16x32_bf16(qf[2*ec],   kf0, sa, 0, 0, 0);
            sb = __builtin_amdgcn_mfma_f32_16x16x32_bf16(qf[2*ec+1], kf1, sb, 0, 0, 0);
        }

        // ---- fixed-shift softmax: P = exp(s-1), publish to shared Pt ----
        #pragma unroll
        for (int r = 0; r < 4; r++) {
            unsigned short pb = f2bf(__expf((sa[r] + sb[r]) - 1.0f));
            l_lane[r] += bf2f(pb);
            Pt[rg][(quad * 4 + r) * PT_STRIDE + kh * 16 + nm] = pb;
        }

        // raw barrier: waits DS only — staging/V loads stay in flight
        asm volatile("s_waitcnt lgkmcnt(0)" ::: "memory");
        __builtin_amdgcn_s_barrier();
        asm volatile("" ::: "memory");

        bf16x8 pf = *(const bf16x8*)(&Pt[rg][nm * PT_STRIDE + quad * 8]);

        // ---- PV (16 col-tiles x K=32) ----
        #pragma unroll
        for (int tt = 0; tt < 16; tt++)
            O[tt] = __builtin_amdgcn_mfma_f32_16x16x32_bf16(pf, vf[tt], O[tt], 0, 0, 0);
    }

    // ---- epilogue: combine l across the kh pair, scale, write, sumsq ----
    float lv[4];
    #pragma unroll
    for (int r = 0; r < 4; r++) {
        float v = l_lane[r];
        #pragma unroll
        for (int o = 1; o < 16; o <<= 1) v += __shfl_xor(v, o);
        lv[r] = v;                         // sum over this wave's 16 keys
    }
    if (nm == 0) {
        #pragma unroll
        for (int r = 0; r < 4; r++) Lred[rg][kh][quad * 4 + r] = lv[r];
    }
    __syncthreads();
    float linv[4];
    #pragma unroll
    for (int r = 0; r < 4; r++)
        linv[r] = 1.0f / (Lred[rg][0][quad * 4 + r] + Lred[rg][1][quad * 4 + r]);

    float ss = 0.0f;
    #pragma unroll
    for (int tt = 0; tt < 16; tt++) {
        #pragma unroll
        for (int r = 0; r < 4; r++) {
            float val = O[tt][r] * linv[r];
            int row = q0 + rg * 16 + quad * 4 + r;
            int col = kh * 256 + tt * 16 + nm;
            out[((size_t)row * B_SZ + b) * H_DIM + col] = val;
            ss += val * val;
        }
    }
    #pragma unroll
    for (int o = 1; o < 64; o <<= 1) ss += __shfl_xor(ss, o);
    if (lane == 0) atomicAdd(sumsq, ss);
}

// ---- Kernel 3: global-norm rescale ----------------------------------------
__global__ void scale_kernel(float* __restrict__ out,
                             const float* __restrict__ sumsq) {
    size_t idx = ((size_t)blockIdx.x * blockDim.x + threadIdx.x) * 4;
    float rs = 1.0f / sqrtf(*sumsq);
    float4 v = *(float4*)(out + idx);
    v.x *= rs; v.y *= rs; v.z *= rs; v.w *= rs;
    *(float4*)(out + idx) = v;
}

extern "C" void kernel_launch(void* const* d_in, const int* in_sizes, int n_in,
                              void* d_out, int out_size, void* d_ws, size_t ws_size,
                              hipStream_t stream) {
    const float* x = (const float*)d_in[0];
    const float* h = (const float*)d_in[1];
    float* out = (float*)d_out;

    unsigned short* Xn = (unsigned short*)d_ws;                  // 8.4 MB
    unsigned short* Vp = Xn + (size_t)B_SZ * N_TOK * E_DIM;      // 16.8 MB
    float* sumsq = (float*)(Vp + (size_t)B_SZ * N_TOK * H_DIM);  // 4 B

    hipMemsetAsync(sumsq, 0, sizeof(float), stream);
    prep_kernel<<<(N_TOK * B_SZ) / 4 + (N_TOK / 32) * (H_DIM / 32) * B_SZ,
                  256, 0, stream>>>(x, h, Xn, Vp);
    flash_kernel<<<dim3(B_SZ, N_TOK / 32), 256, 0, stream>>>(Xn, Vp, out, sumsq);
    scale_kernel<<<out_size / (4 * 256), 256, 0, stream>>>(out, sumsq);
}